// Round 1
// baseline (171.815 us; speedup 1.0000x reference)
//
#include <hip/hip_runtime.h>

// bf16 MFMA fragment types per CDNA4 guide (compile-verified on gfx950)
typedef short bf16x8 __attribute__((ext_vector_type(8)));
typedef float f32x4 __attribute__((ext_vector_type(4)));

// round-to-nearest-even float -> bf16 (bit trick, exact RNE for finite values)
__device__ __forceinline__ short f2bf(float f) {
    unsigned u = __float_as_uint(f);
    u += 0x7fffu + ((u >> 16) & 1u);
    return (short)(u >> 16);
}

// One sample (16x16 matrix) per wave. Chain A_{s+1} = x * A_s via
// mfma_f32_16x16x32_bf16 (K padded 16->32 with zeros on lanes 32..63).
// C/D layout (verified): lane holds C[4*quad+r][n], n=lane&15, quad=lane>>4.
// A layout (verified):   lane holds A[m=lane&15][k=8*quad+j], j=0..7.
// B layout (mirror):     lane holds B[k=8*quad+j][n=lane&15].
__global__ __launch_bounds__(256) void acoef_kernel(
    const float* __restrict__ x,
    const float* __restrict__ coef,
    float* __restrict__ out)
{
    const int lane = threadIdx.x & 63;
    const int wave = threadIdx.x >> 6;
    const int b = blockIdx.x * 4 + wave;
    const float* __restrict__ xb = x + (size_t)b * 256;

    const int n = lane & 15;   // col (C), n (B), m (A)
    const int q = lane >> 4;   // quad

    // ---- x in A layout and B layout (bf16, zero for k>=16 i.e. q>=2) ----
    bf16x8 xA = {0,0,0,0,0,0,0,0};
    bf16x8 xB = {0,0,0,0,0,0,0,0};
    if (q < 2) {
        // A[m][k0..k0+7]: 8 consecutive floats of row m
        const float4 a0 = *(const float4*)(xb + n * 16 + q * 8);
        const float4 a1 = *(const float4*)(xb + n * 16 + q * 8 + 4);
        xA[0] = f2bf(a0.x); xA[1] = f2bf(a0.y); xA[2] = f2bf(a0.z); xA[3] = f2bf(a0.w);
        xA[4] = f2bf(a1.x); xA[5] = f2bf(a1.y); xA[6] = f2bf(a1.z); xA[7] = f2bf(a1.w);
        // B[k0+j][n]: column n, rows k0..k0+7 (stride-16 gather, L1/L2 resident)
        #pragma unroll
        for (int j = 0; j < 8; ++j)
            xB[j] = f2bf(xb[(q * 8 + j) * 16 + n]);
    }

    f32x4 acc = {0.f, 0.f, 0.f, 0.f};
    acc = __builtin_amdgcn_mfma_f32_16x16x32_bf16(xA, xB, acc, 0, 0, 0); // x^2

    // C->B transform source lanes (constant across steps):
    // target (k=q*8+j, n) lives at src lane = n + 16*(k>>2) = n + 32q + 16*(j>>2),
    // register j&3. Wrap to [0,64) for the padded quads (result masked to 0).
    const int src0 = (n + 32 * q) & 63;        // j = 0..3
    const int src1 = (n + 32 * q + 16) & 63;   // j = 4..7

    const bool diagsel = ((n >> 2) == q);      // this lane holds C[n][n] in reg n&3
    float tr[10];

    #pragma unroll
    for (int s = 0; s < 10; ++s) {
        // diagonal partial of C = x^{s+2}
        float selA = (lane & 1) ? acc[1] : acc[0];
        float selB = (lane & 1) ? acc[3] : acc[2];
        float dv   = (lane & 2) ? selB : selA;
        tr[s] = diagsel ? dv : 0.0f;

        if (s < 9) {
            // move C into B-operand layout via wave shuffles (no LDS, no barrier)
            float v0 = __shfl(acc[0], src0);
            float v1 = __shfl(acc[1], src0);
            float v2 = __shfl(acc[2], src0);
            float v3 = __shfl(acc[3], src0);
            float v4 = __shfl(acc[0], src1);
            float v5 = __shfl(acc[1], src1);
            float v6 = __shfl(acc[2], src1);
            float v7 = __shfl(acc[3], src1);
            bf16x8 bfrag = {0,0,0,0,0,0,0,0};
            if (q < 2) {
                bfrag[0] = f2bf(v0); bfrag[1] = f2bf(v1);
                bfrag[2] = f2bf(v2); bfrag[3] = f2bf(v3);
                bfrag[4] = f2bf(v4); bfrag[5] = f2bf(v5);
                bfrag[6] = f2bf(v6); bfrag[7] = f2bf(v7);
            }
            f32x4 z = {0.f, 0.f, 0.f, 0.f};
            acc = __builtin_amdgcn_mfma_f32_16x16x32_bf16(xA, bfrag, z, 0, 0, 0);
        }
    }

    // wave-reduce each trace; lane s keeps t_s
    float tsel = 0.0f;
    #pragma unroll
    for (int s = 0; s < 10; ++s) {
        float v = tr[s];
        #pragma unroll
        for (int m = 1; m < 64; m <<= 1) v += __shfl_xor(v, m);
        if (lane == s) tsel = v;
    }

    // lane i<10: term_i = 256^{-i} * sum_j coef[i,j] * (t_i/256)^{j+1}
    float contrib = 0.0f;
    if (lane < 10) {
        const float4 c = *(const float4*)(coef + lane * 4);
        float sv = tsel * (1.0f / 256.0f);
        float h = fmaf(sv, c.w, c.z);
        h = fmaf(sv, h, c.y);
        h = fmaf(sv, h, c.x);
        contrib = ldexpf(sv * h, -8 * lane);   // * 256^{-lane}
    }
    #pragma unroll
    for (int m = 1; m < 64; m <<= 1) contrib += __shfl_xor(contrib, m);
    if (lane == 0) out[b] = contrib;
}

extern "C" void kernel_launch(void* const* d_in, const int* in_sizes, int n_in,
                              void* d_out, int out_size, void* d_ws, size_t ws_size,
                              hipStream_t stream) {
    const float* x    = (const float*)d_in[0];   // [65536, 16, 16] fp32
    const float* coef = (const float*)d_in[1];   // [10, 4] fp32
    float* out        = (float*)d_out;           // [65536] fp32
    const int B = in_sizes[0] / 256;             // 65536 samples
    acoef_kernel<<<dim3(B / 4), dim3(256), 0, stream>>>(x, coef, out);
}

// Round 3
// 103.822 us; speedup vs baseline: 1.6549x; 1.6549x over previous
//
#include <hip/hip_runtime.h>

typedef __fp16 f16x4 __attribute__((ext_vector_type(4)));
typedef __fp16 f16x2 __attribute__((ext_vector_type(2)));
typedef float f32x4 __attribute__((ext_vector_type(4)));

// Full-rate VALU cross-lane add via DPP (rocPRIM wave64 reduction pattern).
// row_shr:1,2,4,8 reduce within each 16-lane row (accumulating upward),
// row_bcast:15/31 merge rows; total lands in lane 63.
template <int CTRL>
__device__ __forceinline__ float dpp_add(float v) {
    int s = __builtin_amdgcn_update_dpp(0, __float_as_int(v), CTRL, 0xf, 0xf, true);
    return v + __int_as_float(s);
}

__device__ __forceinline__ float wave_sum_uniform(float v) {
    v = dpp_add<0x111>(v);  // row_shr:1
    v = dpp_add<0x112>(v);  // row_shr:2
    v = dpp_add<0x114>(v);  // row_shr:4
    v = dpp_add<0x118>(v);  // row_shr:8
    v = dpp_add<0x142>(v);  // row_bcast:15
    v = dpp_add<0x143>(v);  // row_bcast:31
    return __int_as_float(__builtin_amdgcn_readlane(__float_as_int(v), 63));
}

// One 16x16 sample per wave, chained via mfma_f32_16x16x16_f16 (K=16 exact).
// Key identity: for this shape the C/D layout (row=4q+r, col=lane&15) equals
// the B-operand layout (k=4q+j, n=lane&15), so the accumulator feeds the next
// MFMA's B operand with just an fp32->fp16 pack — no cross-lane transform.
__global__ __launch_bounds__(256) void acoef_kernel(
    const float* __restrict__ x,
    const float* __restrict__ coef,
    float* __restrict__ out)
{
    const int lane = threadIdx.x & 63;
    const int wave = threadIdx.x >> 6;
    const int b = blockIdx.x * 4 + wave;
    const float* __restrict__ xb = x + (size_t)b * 256;

    const int n = lane & 15;   // col (C) / n (B) / m (A)
    const int q = lane >> 4;   // quad -> k block

    // A operand: A[m=n][k=4q+j] = 4 contiguous floats of row n
    const float4 a = *(const float4*)(xb + n * 16 + 4 * q);
    f16x2 alo = __builtin_amdgcn_cvt_pkrtz(a.x, a.y);
    f16x2 ahi = __builtin_amdgcn_cvt_pkrtz(a.z, a.w);
    f16x4 xA = __builtin_shufflevector(alo, ahi, 0, 1, 2, 3);

    // B operand: B[k=4q+j][n] = column n, rows 4q..4q+3 (each 16-lane group
    // reads one contiguous 64B row -> coalesced)
    float b0 = xb[(4 * q + 0) * 16 + n];
    float b1 = xb[(4 * q + 1) * 16 + n];
    float b2 = xb[(4 * q + 2) * 16 + n];
    float b3 = xb[(4 * q + 3) * 16 + n];
    f16x2 blo = __builtin_amdgcn_cvt_pkrtz(b0, b1);
    f16x2 bhi = __builtin_amdgcn_cvt_pkrtz(b2, b3);
    f16x4 xB = __builtin_shufflevector(blo, bhi, 0, 1, 2, 3);

    const f32x4 zero = {0.f, 0.f, 0.f, 0.f};
    f32x4 acc = __builtin_amdgcn_mfma_f32_16x16x16f16(xA, xB, zero, 0, 0, 0); // x^2

    const bool diagsel = ((n >> 2) == q);  // lane holds C[n][n] in reg n&3
    float tr[10];

    #pragma unroll
    for (int s = 0; s < 10; ++s) {
        // diagonal partial of C = x^{s+2}
        float selA = (n & 1) ? acc[1] : acc[0];
        float selB = (n & 1) ? acc[3] : acc[2];
        float dv   = (n & 2) ? selB : selA;
        tr[s] = diagsel ? dv : 0.0f;

        if (s < 9) {
            // C is already in B layout: just pack fp32 -> fp16
            f16x2 lo = __builtin_amdgcn_cvt_pkrtz(acc[0], acc[1]);
            f16x2 hi = __builtin_amdgcn_cvt_pkrtz(acc[2], acc[3]);
            f16x4 bf = __builtin_shufflevector(lo, hi, 0, 1, 2, 3);
            acc = __builtin_amdgcn_mfma_f32_16x16x16f16(xA, bf, zero, 0, 0, 0);
        }
    }

    // Reduce each trace to a wave-uniform scalar, then evaluate the
    // polynomial redundantly in all lanes (no final reduction needed).
    constexpr float SC[10] = {0x1p0f,  0x1p-8f,  0x1p-16f, 0x1p-24f, 0x1p-32f,
                              0x1p-40f, 0x1p-48f, 0x1p-56f, 0x1p-64f, 0x1p-72f};
    float result = 0.0f;
    #pragma unroll
    for (int s = 0; s < 10; ++s) {
        float t  = wave_sum_uniform(tr[s]);
        float sv = t * 0x1p-8f;  // t / 256
        float h = fmaf(sv, coef[s * 4 + 3], coef[s * 4 + 2]);
        h = fmaf(sv, h, coef[s * 4 + 1]);
        h = fmaf(sv, h, coef[s * 4 + 0]);
        result = fmaf(sv * h, SC[s], result);  // * 256^{-s}
    }
    if (lane == 0) out[b] = result;
}

extern "C" void kernel_launch(void* const* d_in, const int* in_sizes, int n_in,
                              void* d_out, int out_size, void* d_ws, size_t ws_size,
                              hipStream_t stream) {
    const float* x    = (const float*)d_in[0];   // [65536, 16, 16] fp32
    const float* coef = (const float*)d_in[1];   // [10, 4] fp32
    float* out        = (float*)d_out;           // [65536] fp32
    const int B = in_sizes[0] / 256;             // 65536 samples
    acoef_kernel<<<dim3(B / 4), dim3(256), 0, stream>>>(x, coef, out);
}

// Round 4
// 99.422 us; speedup vs baseline: 1.7281x; 1.0443x over previous
//
#include <hip/hip_runtime.h>

typedef __fp16 f16x4 __attribute__((ext_vector_type(4)));
typedef __fp16 f16x2 __attribute__((ext_vector_type(2)));
typedef float f32x4 __attribute__((ext_vector_type(4)));

__device__ __forceinline__ f16x4 cat(f16x2 lo, f16x2 hi) {
    return __builtin_shufflevector(lo, hi, 0, 1, 2, 3);
}
__device__ __forceinline__ f16x2 u2h(unsigned v) {
    union { unsigned u; f16x2 h; } x; x.u = v; return x.h;
}

// quad_perm DPP adds for the final 4-lane sum
template <int CTRL>
__device__ __forceinline__ float dpp_add(float v) {
    int s = __builtin_amdgcn_update_dpp(0, __float_as_int(v), CTRL, 0xf, 0xf, true);
    return v + __int_as_float(s);
}

// One 16x16 sample per wave. Chain A_{s+1} = x*A_s via mfma_f32_16x16x16_f16:
// C/D layout (row=4q+r, col=n) == B layout (k=4q+j, n) for this shape, so the
// accumulator feeds the next MFMA's B with just a pkrtz pack.
// Trace reduction is ALSO done with MFMA: pr-matrix * selector, then ones * C1
// puts t_n in every lane of column n (lane-parallel epilogue, no DPP trees).
__global__ __launch_bounds__(256) void acoef_kernel(
    const float* __restrict__ x,
    const float* __restrict__ coef,
    float* __restrict__ out)
{
    const int lane = threadIdx.x & 63;
    const int wave = threadIdx.x >> 6;
    const int b = blockIdx.x * 4 + wave;
    const float* __restrict__ xb = x + (size_t)b * 256;

    const int n = lane & 15;   // col (C) / n (B) / m (A)
    const int q = lane >> 4;   // quad -> k block

    // A operand: A[m=n][k=4q+j] = 4 contiguous floats of row n
    const float4 a = *(const float4*)(xb + n * 16 + 4 * q);
    f16x4 xA = cat(__builtin_amdgcn_cvt_pkrtz(a.x, a.y),
                   __builtin_amdgcn_cvt_pkrtz(a.z, a.w));

    // B operand: B[k=4q+j][n] = column n, rows 4q..4q+3
    float b0 = xb[(4 * q + 0) * 16 + n];
    float b1 = xb[(4 * q + 1) * 16 + n];
    float b2 = xb[(4 * q + 2) * 16 + n];
    float b3 = xb[(4 * q + 3) * 16 + n];
    f16x4 xB = cat(__builtin_amdgcn_cvt_pkrtz(b0, b1),
                   __builtin_amdgcn_cvt_pkrtz(b2, b3));

    const f32x4 zero = {0.f, 0.f, 0.f, 0.f};
    f32x4 acc = __builtin_amdgcn_mfma_f32_16x16x16f16(xA, xB, zero, 0, 0, 0); // x^2

    const bool diagsel = ((n >> 2) == q);  // lane holds C[n][n] in reg n&3

    // trace partials, packed pairwise to f16 as they are produced
    f16x2 prpk[6];
    float trf = 0.0f;

    #pragma unroll
    for (int s = 0; s < 10; ++s) {
        float selA = (n & 1) ? acc[1] : acc[0];
        float selB = (n & 1) ? acc[3] : acc[2];
        float dv   = (n & 2) ? selB : selA;
        float tr   = diagsel ? dv : 0.0f;
        if (s & 1) prpk[s >> 1] = __builtin_amdgcn_cvt_pkrtz(trf, tr);
        else       trf = tr;

        if (s < 9) {
            f16x4 bf = cat(__builtin_amdgcn_cvt_pkrtz(acc[0], acc[1]),
                           __builtin_amdgcn_cvt_pkrtz(acc[2], acc[3]));
            acc = __builtin_amdgcn_mfma_f32_16x16x16f16(xA, bf, zero, 0, 0, 0);
        }
    }
    prpk[5] = u2h(0u);  // traces 10,11 = 0 (pad for pass 2)

    // Selector B: B[4q+j][n] = (j==n) ? 1 : 0  (f16 1.0 = 0x3C00), q-independent
    unsigned slo = (n == 0 ? 0x3C00u : 0u) | (n == 1 ? 0x3C000000u : 0u);
    unsigned shi = (n == 2 ? 0x3C00u : 0u) | (n == 3 ? 0x3C000000u : 0u);
    f16x4 selB = cat(u2h(slo), u2h(shi));
    f16x4 onesA = cat(u2h(0x3C003C00u), u2h(0x3C003C00u));

    // Epilogue: pass p reduces traces 4p..4p+3; lane column n<4 owns trace 4p+n.
    float result = 0.0f;
    #pragma unroll
    for (int p = 0; p < 3; ++p) {
        // M1: C1[m][n] = sum_q pr[n]@(m,q)   (per-column partial over quads)
        f16x4 Ap = cat(prpk[2 * p], prpk[2 * p + 1]);
        f32x4 c1 = __builtin_amdgcn_mfma_f32_16x16x16f16(Ap, selB, zero, 0, 0, 0);
        // M2: C2[m][n] = sum_k C1[k][n] = t_{4p+n}  (C1 feeds B directly: C==B layout)
        f16x4 Bp = cat(__builtin_amdgcn_cvt_pkrtz(c1[0], c1[1]),
                       __builtin_amdgcn_cvt_pkrtz(c1[2], c1[3]));
        f32x4 c2 = __builtin_amdgcn_mfma_f32_16x16x16f16(onesA, Bp, zero, 0, 0, 0);
        float t = c2[0];  // t_{4p+n} for n<4, 0 otherwise

        int s = 4 * p + n;
        int idx = s > 9 ? 9 : s;                       // clamp coef row (t=0 there anyway)
        const float4 c = *(const float4*)(coef + 4 * idx);
        float sv = t * 0x1p-8f;                        // t / 256
        float h = fmaf(sv, c.w, c.z);
        h = fmaf(sv, h, c.y);
        h = fmaf(sv, h, c.x);
        float scl = __int_as_float((127 - 8 * s) << 23);  // 256^{-s}
        result = fmaf(sv * h, scl, result);
    }

    // sum the 4 per-column results within the quad (lanes 0..3); lane 0 stores
    result = dpp_add<0xB1>(result);  // quad_perm [1,0,3,2]
    result = dpp_add<0x4E>(result);  // quad_perm [2,3,0,1]
    if (lane == 0) out[b] = result;
}

extern "C" void kernel_launch(void* const* d_in, const int* in_sizes, int n_in,
                              void* d_out, int out_size, void* d_ws, size_t ws_size,
                              hipStream_t stream) {
    const float* x    = (const float*)d_in[0];   // [65536, 16, 16] fp32
    const float* coef = (const float*)d_in[1];   // [10, 4] fp32
    float* out        = (float*)d_out;           // [65536] fp32
    const int B = in_sizes[0] / 256;             // 65536 samples
    acoef_kernel<<<dim3(B / 4), dim3(256), 0, stream>>>(x, coef, out);
}

// Round 5
// 96.117 us; speedup vs baseline: 1.7876x; 1.0344x over previous
//
#include <hip/hip_runtime.h>

typedef __fp16 f16x4 __attribute__((ext_vector_type(4)));
typedef __fp16 f16x2 __attribute__((ext_vector_type(2)));
typedef float f32x4 __attribute__((ext_vector_type(4)));

__device__ __forceinline__ f16x4 cat(f16x2 lo, f16x2 hi) {
    return __builtin_shufflevector(lo, hi, 0, 1, 2, 3);
}
__device__ __forceinline__ f16x2 u2h(unsigned v) {
    union { unsigned u; f16x2 h; } x; x.u = v; return x.h;
}
template <int CTRL>
__device__ __forceinline__ float dpp_add(float v) {
    int s = __builtin_amdgcn_update_dpp(0, __float_as_int(v), CTRL, 0xf, 0xf, true);
    return v + __int_as_float(s);
}

// Persistent waves: each wave handles 8 samples (grid-stride), prefetching the
// next sample's 8 raw values into registers while the current sample's serial
// MFMA chain runs — hides the ~600cy L3/HBM latency that dominated round 4.
// Chain A_{s+1}=x*A_s via mfma_f32_16x16x16f16: C/D layout == B layout for
// this shape, so acc feeds the next B with just a pkrtz pack. Trace reduction
// via 2-MFMA passes (pr-matrix * selector, then ones * C1) -> lane-parallel
// polynomial epilogue.
__global__ __launch_bounds__(256, 8) void acoef_kernel(
    const float* __restrict__ x,
    const float* __restrict__ coef,
    float* __restrict__ out,
    int B)
{
    const int lane = threadIdx.x & 63;
    const int wid  = (blockIdx.x * 256 + threadIdx.x) >> 6;  // global wave id
    const int stride = gridDim.x * 4;                        // total waves

    const int n = lane & 15;   // col (C) / n (B) / m (A)
    const int q = lane >> 4;   // quad -> k block
    const bool diagsel = ((n >> 2) == q);

    // ---- loop-invariant epilogue constants ----
    unsigned slo = (n == 0 ? 0x3C00u : 0u) | (n == 1 ? 0x3C000000u : 0u);
    unsigned shi = (n == 2 ? 0x3C00u : 0u) | (n == 3 ? 0x3C000000u : 0u);
    const f16x4 selB  = cat(u2h(slo), u2h(shi));
    const f16x4 onesA = cat(u2h(0x3C003C00u), u2h(0x3C003C00u));
    const f32x4 zero  = {0.f, 0.f, 0.f, 0.f};
    // per-lane coef rows and 256^{-s} scales for passes p=0..2 (s = 4p + n)
    float4 cf[3]; float scl[3];
    #pragma unroll
    for (int p = 0; p < 3; ++p) {
        int s = 4 * p + n;
        int idx = s > 9 ? 9 : s;
        cf[p]  = *(const float4*)(coef + 4 * idx);
        scl[p] = __int_as_float((127 - 8 * s) << 23);
    }

    const int aoff = n * 16 + 4 * q;          // A: row n, cols 4q..4q+3
    const int boff = 4 * q * 16 + n;          // B: col n, rows 4q..4q+3

    // ---- prologue load (sample 0 of this wave) ----
    int s = wid;
    const float* xb = x + (size_t)s * 256;
    float4 a = *(const float4*)(xb + aoff);
    float b0 = xb[boff], b1 = xb[boff + 16], b2 = xb[boff + 32], b3 = xb[boff + 48];

    while (true) {
        const int s2 = s + stride;
        const bool more = (s2 < B);
        // prefetch next sample (clamped to current on the last iter)
        const float* xn = x + (size_t)(more ? s2 : s) * 256;
        float4 an = *(const float4*)(xn + aoff);
        float bn0 = xn[boff], bn1 = xn[boff + 16], bn2 = xn[boff + 32], bn3 = xn[boff + 48];

        // ---- compute current sample ----
        f16x4 xA = cat(__builtin_amdgcn_cvt_pkrtz(a.x, a.y),
                       __builtin_amdgcn_cvt_pkrtz(a.z, a.w));
        f16x4 xB = cat(__builtin_amdgcn_cvt_pkrtz(b0, b1),
                       __builtin_amdgcn_cvt_pkrtz(b2, b3));

        f32x4 acc = __builtin_amdgcn_mfma_f32_16x16x16f16(xA, xB, zero, 0, 0, 0); // x^2

        f16x2 prpk[6];
        float trf = 0.0f;
        #pragma unroll
        for (int st = 0; st < 10; ++st) {
            float selA = (n & 1) ? acc[1] : acc[0];
            float selBv = (n & 1) ? acc[3] : acc[2];
            float dv = (n & 2) ? selBv : selA;
            float tr = diagsel ? dv : 0.0f;
            if (st & 1) prpk[st >> 1] = __builtin_amdgcn_cvt_pkrtz(trf, tr);
            else        trf = tr;

            if (st < 9) {
                f16x4 bf = cat(__builtin_amdgcn_cvt_pkrtz(acc[0], acc[1]),
                               __builtin_amdgcn_cvt_pkrtz(acc[2], acc[3]));
                acc = __builtin_amdgcn_mfma_f32_16x16x16f16(xA, bf, zero, 0, 0, 0);
            }
        }
        prpk[5] = u2h(0u);  // traces 10,11 = 0 pad

        float result = 0.0f;
        #pragma unroll
        for (int p = 0; p < 3; ++p) {
            f16x4 Ap = cat(prpk[2 * p], prpk[2 * p + 1]);
            f32x4 c1 = __builtin_amdgcn_mfma_f32_16x16x16f16(Ap, selB, zero, 0, 0, 0);
            f16x4 Bp = cat(__builtin_amdgcn_cvt_pkrtz(c1[0], c1[1]),
                           __builtin_amdgcn_cvt_pkrtz(c1[2], c1[3]));
            f32x4 c2 = __builtin_amdgcn_mfma_f32_16x16x16f16(onesA, Bp, zero, 0, 0, 0);
            float t = c2[0];             // t_{4p+n} for n<4, else 0
            float sv = t * 0x1p-8f;      // t / 256
            float h = fmaf(sv, cf[p].w, cf[p].z);
            h = fmaf(sv, h, cf[p].y);
            h = fmaf(sv, h, cf[p].x);
            result = fmaf(sv * h, scl[p], result);
        }
        result = dpp_add<0xB1>(result);  // quad_perm [1,0,3,2]
        result = dpp_add<0x4E>(result);  // quad_perm [2,3,0,1]
        if (lane == 0) out[s] = result;

        if (!more) break;
        s = s2; a = an; b0 = bn0; b1 = bn1; b2 = bn2; b3 = bn3;
    }
}

extern "C" void kernel_launch(void* const* d_in, const int* in_sizes, int n_in,
                              void* d_out, int out_size, void* d_ws, size_t ws_size,
                              hipStream_t stream) {
    const float* x    = (const float*)d_in[0];   // [65536, 16, 16] fp32
    const float* coef = (const float*)d_in[1];   // [10, 4] fp32
    float* out        = (float*)d_out;           // [65536] fp32
    const int B = in_sizes[0] / 256;             // 65536 samples
    // 2048 blocks x 4 waves = 8192 waves -> 8 samples per wave, full residency
    acoef_kernel<<<dim3(2048), dim3(256), 0, stream>>>(x, coef, out, B);
}